// Round 1
// baseline (277.860 us; speedup 1.0000x reference)
//
#include <hip/hip_runtime.h>
#include <hip/hip_bf16.h>
#include <math.h>
#include <stdint.h>

// Problem constants (B,S,H) = (8,128,768)
#define S_LEN 128
#define H_DIM 768
#define B_DIM 8
#define NPAIR 8256          // S*(S+1)/2
#define MROWS 1024          // B*S
#define NTOT  3072          // 4*H : [Ax | Bx | Gx | Ay]
#define EPSC  1e-12f

typedef __bf16 bf16x8 __attribute__((ext_vector_type(8)));
typedef float  f32x4  __attribute__((ext_vector_type(4)));

// RNE float -> bf16 (inputs are finite; no NaN handling needed)
static __device__ __forceinline__ unsigned short f2bf(float f) {
  union { float f; unsigned u; } a; a.f = f;
  unsigned u = a.u;
  u += 0x7fffu + ((u >> 16) & 1u);
  return (unsigned short)(u >> 16);
}

// -------------------- convert X,Y to bf16 --------------------
__global__ __launch_bounds__(256) void convert_xy(const float* __restrict__ x,
                                                  const float* __restrict__ y,
                                                  unsigned short* __restrict__ xb,
                                                  unsigned short* __restrict__ yb) {
  int idx = blockIdx.x * 256 + threadIdx.x;     // one float4 per thread
  if (idx >= MROWS * H_DIM / 4) return;
  float4 vx = ((const float4*)x)[idx];
  float4 vy = ((const float4*)y)[idx];
  ushort4 ox; ox.x = f2bf(vx.x); ox.y = f2bf(vx.y); ox.z = f2bf(vx.z); ox.w = f2bf(vx.w);
  ushort4 oy; oy.x = f2bf(vy.x); oy.y = f2bf(vy.y); oy.z = f2bf(vy.z); oy.w = f2bf(vy.w);
  ((ushort4*)xb)[idx] = ox;
  ((ushort4*)yb)[idx] = oy;
}

// -------------------- pack weights: Wb[3072][768] bf16 --------------------
// rows 0..767   : cat_W[n][0..767]       (guide half)
// rows 768..1535: beta_W[n-768][:]
// rows 1536..2303: gamma_W[n-1536][:]
// rows 2304..3071: cat_W[n-2304][768..1535] (visible half)
__global__ __launch_bounds__(256) void pack_w(const float* __restrict__ catW,
                                              const float* __restrict__ betaW,
                                              const float* __restrict__ gammaW,
                                              unsigned short* __restrict__ Wb) {
  int idx = blockIdx.x * 256 + threadIdx.x;     // one float4 per thread
  if (idx >= NTOT * H_DIM / 4) return;
  int e = idx * 4;
  int n = e / H_DIM, k = e % H_DIM;
  const float* src;
  if      (n < 768)  src = catW   + (size_t)n * 1536 + k;
  else if (n < 1536) src = betaW  + (size_t)(n - 768) * 768 + k;
  else if (n < 2304) src = gammaW + (size_t)(n - 1536) * 768 + k;
  else               src = catW   + (size_t)(n - 2304) * 1536 + 768 + k;
  float4 v = *(const float4*)src;
  ushort4 o; o.x = f2bf(v.x); o.y = f2bf(v.y); o.z = f2bf(v.z); o.w = f2bf(v.w);
  *(ushort4*)(Wb + e) = o;
}

// -------------------- per-row mean / 1/(var+eps)^2 of Y --------------------
__global__ __launch_bounds__(256) void row_stats(const float* __restrict__ y,
                                                 float* __restrict__ mean,
                                                 float* __restrict__ inv) {
  int row = blockIdx.x;                         // 0..1023
  const float* yr = y + (size_t)row * H_DIM;
  float s = 0.f, s2 = 0.f;
  for (int o = threadIdx.x; o < H_DIM; o += 256) { float v = yr[o]; s += v; s2 += v * v; }
  for (int off = 32; off > 0; off >>= 1) { s += __shfl_down(s, off); s2 += __shfl_down(s2, off); }
  __shared__ float ls[4], ls2[4];
  if ((threadIdx.x & 63) == 0) { ls[threadIdx.x >> 6] = s; ls2[threadIdx.x >> 6] = s2; }
  __syncthreads();
  if (threadIdx.x == 0) {
    float S1 = ls[0] + ls[1] + ls[2] + ls[3];
    float S2 = ls2[0] + ls2[1] + ls2[2] + ls2[3];
    float m = S1 / H_DIM;
    float var = S2 / H_DIM - m * m;
    float st = var + EPSC;                      // reference: std = (var+eps)**2
    mean[row] = m;
    inv[row] = 1.0f / (st * st);
  }
}

// -------------------- MFMA GEMM: P[m][n] = A[m][:] . W[n][:] --------------------
// A = Xb for n<2304, Yb for n>=2304 (both [1024][768] bf16, k-contiguous)
// W = Wb [3072][768] bf16, k-contiguous (B^T layout)
__device__ __forceinline__ void gload_lds16(const void* g, void* l) {
  __builtin_amdgcn_global_load_lds(
      (const __attribute__((address_space(1))) unsigned int*)(uintptr_t)g,
      (__attribute__((address_space(3))) unsigned int*)(uintptr_t)l,
      16, 0, 0);
}

__global__ __launch_bounds__(256) void gemm_bt(const unsigned short* __restrict__ Xb,
                                               const unsigned short* __restrict__ Yb,
                                               const unsigned short* __restrict__ Wb,
                                               float* __restrict__ P) {
  __shared__ unsigned short As[128 * 32];  // [m][k], k contiguous
  __shared__ unsigned short Bs[128 * 32];  // [n][k]
  const int m0 = blockIdx.x * 128;
  const int n0 = blockIdx.y * 128;
  const unsigned short* A = (n0 < 2304) ? Xb : Yb;
  const unsigned short* Arow = A + (size_t)m0 * H_DIM;
  const unsigned short* Brow = Wb + (size_t)n0 * H_DIM;

  const int tid  = threadIdx.x;
  const int lane = tid & 63;
  const int wave = tid >> 6;
  const int wm = (wave >> 1) * 64;
  const int wn = (wave & 1) * 64;
  const int quad = lane >> 4;
  const int r    = lane & 15;

  const int ar = tid >> 2;          // staging row 0..63
  const int ac = (tid & 3) * 8;     // staging col {0,8,16,24}

  f32x4 acc[4][4] = {};

  for (int k0 = 0; k0 < H_DIM; k0 += 32) {
    gload_lds16(Arow + (size_t)ar * H_DIM + k0 + ac,        &As[tid * 8]);
    gload_lds16(Arow + (size_t)(ar + 64) * H_DIM + k0 + ac, &As[2048 + tid * 8]);
    gload_lds16(Brow + (size_t)ar * H_DIM + k0 + ac,        &Bs[tid * 8]);
    gload_lds16(Brow + (size_t)(ar + 64) * H_DIM + k0 + ac, &Bs[2048 + tid * 8]);
    __syncthreads();   // drains vmcnt before barrier -> staging complete

    bf16x8 af[4], bfr[4];
#pragma unroll
    for (int mi = 0; mi < 4; ++mi)
      af[mi] = *(const bf16x8*)&As[(wm + mi * 16 + r) * 32 + quad * 8];
#pragma unroll
    for (int ni = 0; ni < 4; ++ni)
      bfr[ni] = *(const bf16x8*)&Bs[(wn + ni * 16 + r) * 32 + quad * 8];
#pragma unroll
    for (int mi = 0; mi < 4; ++mi)
#pragma unroll
      for (int ni = 0; ni < 4; ++ni)
        acc[mi][ni] = __builtin_amdgcn_mfma_f32_16x16x32_bf16(af[mi], bfr[ni], acc[mi][ni], 0, 0, 0);
    __syncthreads();
  }

#pragma unroll
  for (int mi = 0; mi < 4; ++mi) {
#pragma unroll
    for (int ni = 0; ni < 4; ++ni) {
      const int row = m0 + wm + mi * 16 + quad * 4;   // C/D: col=lane&15, row=quad*4+reg
      const int col = n0 + wn + ni * 16 + r;
#pragma unroll
      for (int reg = 0; reg < 4; ++reg)
        P[(size_t)(row + reg) * NTOT + col] = acc[mi][ni][reg];
    }
  }
}

// -------------------- epilogue: gather + elementwise --------------------
__global__ __launch_bounds__(192) void epilogue(const float* __restrict__ P,
                                                const float* __restrict__ Yf,
                                                const float* __restrict__ mean,
                                                const float* __restrict__ inv,
                                                const float* __restrict__ cat_b,
                                                const float* __restrict__ beta,
                                                const float* __restrict__ gamma,
                                                float* __restrict__ out) {
  const int p = blockIdx.x;   // 0..8255
  const int b = blockIdx.y;   // 0..7
  // find i: off(i) <= p < off(i+1), off(i) = i*(2S-i+1)/2  (triu incl. diagonal)
  int i = (int)((2.0 * S_LEN + 1.0
                 - sqrt((2.0 * S_LEN + 1.0) * (2.0 * S_LEN + 1.0) - 8.0 * (double)p)) * 0.5);
  if (i < 0) i = 0;
  if (i > S_LEN - 1) i = S_LEN - 1;
  while ((i + 1) * (2 * S_LEN - i) / 2 <= p) ++i;
  while (i * (2 * S_LEN - i + 1) / 2 > p) --i;
  const int j = i + (p - i * (2 * S_LEN - i + 1) / 2);

  const int o = threadIdx.x * 4;                 // 192 threads x float4 = 768
  const size_t ri = (size_t)(b * S_LEN + i) * NTOT;
  const size_t rj = (size_t)(b * S_LEN + j) * NTOT;
  float4 ax = *(const float4*)(P + ri + o);
  float4 bx = *(const float4*)(P + ri + 768 + o);
  float4 gx = *(const float4*)(P + ri + 1536 + o);
  float4 ay = *(const float4*)(P + rj + 2304 + o);
  float4 yv = *(const float4*)(Yf + (size_t)(b * S_LEN + j) * H_DIM + o);
  const float m  = mean[b * S_LEN + j];
  const float iv = inv[b * S_LEN + j];
  float4 cb = *(const float4*)(cat_b + o);
  float4 be = *(const float4*)(beta + o);
  float4 ga = *(const float4*)(gamma + o);
  float4 rr;
  rr.x = 0.5f * (fmaxf(ax.x + ay.x + cb.x, 0.f) + (yv.x - m) * iv * (gx.x + ga.x) + bx.x + be.x);
  rr.y = 0.5f * (fmaxf(ax.y + ay.y + cb.y, 0.f) + (yv.y - m) * iv * (gx.y + ga.y) + bx.y + be.y);
  rr.z = 0.5f * (fmaxf(ax.z + ay.z + cb.z, 0.f) + (yv.z - m) * iv * (gx.z + ga.z) + bx.z + be.z);
  rr.w = 0.5f * (fmaxf(ax.w + ay.w + cb.w, 0.f) + (yv.w - m) * iv * (gx.w + ga.w) + bx.w + be.w);
  *(float4*)(out + ((size_t)b * NPAIR + p) * H_DIM + o) = rr;
}

extern "C" void kernel_launch(void* const* d_in, const int* in_sizes, int n_in,
                              void* d_out, int out_size, void* d_ws, size_t ws_size,
                              hipStream_t stream) {
  const float* x      = (const float*)d_in[0];  // (8,128,768)
  const float* y      = (const float*)d_in[1];  // (8,128,768)
  const float* catW   = (const float*)d_in[2];  // (768,1536)
  const float* catb   = (const float*)d_in[3];  // (768,)
  const float* beta   = (const float*)d_in[4];  // (768,)
  const float* gamma  = (const float*)d_in[5];  // (768,)
  const float* betaW  = (const float*)d_in[6];  // (768,768)
  const float* gammaW = (const float*)d_in[7];  // (768,768)

  // workspace layout (~20.5 MB total)
  char* ws = (char*)d_ws;
  unsigned short* Xb   = (unsigned short*)(ws);             // 1024*768*2 = 1.5 MB
  unsigned short* Yb   = (unsigned short*)(ws + 1572864);   // 1.5 MB
  unsigned short* Wb   = (unsigned short*)(ws + 3145728);   // 3072*768*2 = 4.5 MB
  float*          P    = (float*)(ws + 7864320);            // 1024*3072*4 = 12.6 MB
  float*          mean = (float*)(ws + 20447232);           // 4 KB
  float*          inv  = (float*)(ws + 20451328);           // 4 KB
  float*          out  = (float*)d_out;                     // (8,8256,768) fp32

  convert_xy<<<768, 256, 0, stream>>>(x, y, Xb, Yb);
  pack_w<<<2304, 256, 0, stream>>>(catW, betaW, gammaW, Wb);
  row_stats<<<1024, 256, 0, stream>>>(y, mean, inv);
  gemm_bt<<<dim3(8, 24), 256, 0, stream>>>(Xb, Yb, Wb, P);
  epilogue<<<dim3(NPAIR, B_DIM), 192, 0, stream>>>(P, y, mean, inv, catb, beta, gamma, out);
}

// Round 2
// 239.216 us; speedup vs baseline: 1.1615x; 1.1615x over previous
//
#include <hip/hip_runtime.h>
#include <hip/hip_bf16.h>
#include <math.h>
#include <stdint.h>

// Problem constants (B,S,H) = (8,128,768)
#define S_LEN 128
#define H_DIM 768
#define B_DIM 8
#define NPAIR 8256          // S*(S+1)/2
#define MROWS 1024          // B*S
#define NTOT  3072          // 4*H : [Ax | Bx | Gx | Ay]
#define EPSC  1e-12f
#define CHUNK 8             // pairs per epilogue block (NPAIR = 1032*8 exactly)

typedef __bf16 bf16x8 __attribute__((ext_vector_type(8)));
typedef float  f32x4  __attribute__((ext_vector_type(4)));

// RNE float -> bf16 (inputs finite)
static __device__ __forceinline__ unsigned short f2bf(float f) {
  union { float f; unsigned u; } a; a.f = f;
  unsigned u = a.u;
  u += 0x7fffu + ((u >> 16) & 1u);
  return (unsigned short)(u >> 16);
}
static __device__ __forceinline__ float bf2f(unsigned short s) {
  union { unsigned u; float f; } a; a.u = ((unsigned)s) << 16;
  return a.f;
}
static __device__ __forceinline__ float4 ld_bf4(const unsigned short* p) {
  ushort4 u = *(const ushort4*)p;
  float4 f; f.x = bf2f(u.x); f.y = bf2f(u.y); f.z = bf2f(u.z); f.w = bf2f(u.w);
  return f;
}

// -------------------- prep: convert x,y -> bf16, row stats, pack W --------------------
// blocks 0..1023          : row conv (x,y) + mean/inv of y row
// blocks 1024..1024+2303  : pack_w chunk (256 threads x float4)
__global__ __launch_bounds__(256) void prep(const float* __restrict__ x,
                                            const float* __restrict__ y,
                                            const float* __restrict__ catW,
                                            const float* __restrict__ betaW,
                                            const float* __restrict__ gammaW,
                                            unsigned short* __restrict__ Xb,
                                            unsigned short* __restrict__ Yb,
                                            unsigned short* __restrict__ Wb,
                                            float* __restrict__ mean,
                                            float* __restrict__ inv) {
  const int bid = blockIdx.x;
  const int tid = threadIdx.x;
  if (bid < MROWS) {
    // ---- convert one row of x and y; stats on y ----
    const int row = bid;
    float s = 0.f, s2 = 0.f;
    if (tid < 192) {
      const int o = tid * 4;
      float4 vx = *(const float4*)(x + (size_t)row * H_DIM + o);
      float4 vy = *(const float4*)(y + (size_t)row * H_DIM + o);
      ushort4 ox; ox.x = f2bf(vx.x); ox.y = f2bf(vx.y); ox.z = f2bf(vx.z); ox.w = f2bf(vx.w);
      ushort4 oy; oy.x = f2bf(vy.x); oy.y = f2bf(vy.y); oy.z = f2bf(vy.z); oy.w = f2bf(vy.w);
      *(ushort4*)(Xb + (size_t)row * H_DIM + o) = ox;
      *(ushort4*)(Yb + (size_t)row * H_DIM + o) = oy;
      s  = vy.x + vy.y + vy.z + vy.w;
      s2 = vy.x * vy.x + vy.y * vy.y + vy.z * vy.z + vy.w * vy.w;
    }
    for (int off = 32; off > 0; off >>= 1) { s += __shfl_down(s, off); s2 += __shfl_down(s2, off); }
    __shared__ float ls[4], ls2[4];
    if ((tid & 63) == 0) { ls[tid >> 6] = s; ls2[tid >> 6] = s2; }
    __syncthreads();
    if (tid == 0) {
      float S1 = ls[0] + ls[1] + ls[2] + ls[3];
      float S2 = ls2[0] + ls2[1] + ls2[2] + ls2[3];
      float m = S1 / H_DIM;
      float var = S2 / H_DIM - m * m;
      float st = var + EPSC;                 // reference: std = (var+eps)**2
      mean[row] = m;
      inv[row] = 1.0f / (st * st);
    }
  } else {
    // ---- pack weights: Wb[3072][768] bf16 ----
    int idx = (bid - MROWS) * 256 + tid;     // one float4 per thread
    int e = idx * 4;
    int n = e / H_DIM, k = e % H_DIM;
    const float* src;
    if      (n < 768)  src = catW   + (size_t)n * 1536 + k;
    else if (n < 1536) src = betaW  + (size_t)(n - 768) * 768 + k;
    else if (n < 2304) src = gammaW + (size_t)(n - 1536) * 768 + k;
    else               src = catW   + (size_t)(n - 2304) * 1536 + 768 + k;
    float4 v = *(const float4*)src;
    ushort4 o; o.x = f2bf(v.x); o.y = f2bf(v.y); o.z = f2bf(v.z); o.w = f2bf(v.w);
    *(ushort4*)(Wb + e) = o;
  }
}

// -------------------- MFMA GEMM 64x64 tiles: P[m][n] = A[m][:] . W[n][:] (bf16 out) --------------------
__device__ __forceinline__ void gload_lds16(const void* g, void* l) {
  __builtin_amdgcn_global_load_lds(
      (const __attribute__((address_space(1))) unsigned int*)(uintptr_t)g,
      (__attribute__((address_space(3))) unsigned int*)(uintptr_t)l,
      16, 0, 0);
}

__global__ __launch_bounds__(256) void gemm_bt(const unsigned short* __restrict__ Xb,
                                               const unsigned short* __restrict__ Yb,
                                               const unsigned short* __restrict__ Wb,
                                               unsigned short* __restrict__ P) {
  __shared__ unsigned short As[64 * 32];   // [m][k], k contiguous
  __shared__ unsigned short Bs[64 * 32];   // [n][k]
  const int m0 = blockIdx.x * 64;
  const int n0 = blockIdx.y * 64;
  const unsigned short* A = (n0 < 2304) ? Xb : Yb;
  const unsigned short* Arow = A + (size_t)m0 * H_DIM;
  const unsigned short* Brow = Wb + (size_t)n0 * H_DIM;

  const int tid  = threadIdx.x;
  const int lane = tid & 63;
  const int wave = tid >> 6;
  const int wm = (wave >> 1) * 32;
  const int wn = (wave & 1) * 32;
  const int quad = lane >> 4;
  const int r    = lane & 15;

  const int ar = tid >> 2;          // staging row 0..63
  const int ac = (tid & 3) * 8;     // staging col {0,8,16,24}

  f32x4 acc[2][2] = {};

  for (int k0 = 0; k0 < H_DIM; k0 += 32) {
    gload_lds16(Arow + (size_t)ar * H_DIM + k0 + ac, &As[tid * 8]);
    gload_lds16(Brow + (size_t)ar * H_DIM + k0 + ac, &Bs[tid * 8]);
    __syncthreads();   // drains vmcnt before barrier -> staging complete

    bf16x8 af[2], bfr[2];
#pragma unroll
    for (int mi = 0; mi < 2; ++mi)
      af[mi] = *(const bf16x8*)&As[(wm + mi * 16 + r) * 32 + quad * 8];
#pragma unroll
    for (int ni = 0; ni < 2; ++ni)
      bfr[ni] = *(const bf16x8*)&Bs[(wn + ni * 16 + r) * 32 + quad * 8];
#pragma unroll
    for (int mi = 0; mi < 2; ++mi)
#pragma unroll
      for (int ni = 0; ni < 2; ++ni)
        acc[mi][ni] = __builtin_amdgcn_mfma_f32_16x16x32_bf16(af[mi], bfr[ni], acc[mi][ni], 0, 0, 0);
    __syncthreads();
  }

#pragma unroll
  for (int mi = 0; mi < 2; ++mi) {
#pragma unroll
    for (int ni = 0; ni < 2; ++ni) {
      const int row = m0 + wm + mi * 16 + quad * 4;   // C/D: col=lane&15, row=quad*4+reg
      const int col = n0 + wn + ni * 16 + r;
#pragma unroll
      for (int reg = 0; reg < 4; ++reg)
        P[(size_t)(row + reg) * NTOT + col] = f2bf(acc[mi][ni][reg]);
    }
  }
}

// -------------------- epilogue: 8 pairs per block, i-row cached in registers --------------------
__global__ __launch_bounds__(192) void epilogue(const unsigned short* __restrict__ P,
                                                const float* __restrict__ Yf,
                                                const float* __restrict__ mean,
                                                const float* __restrict__ inv,
                                                const float* __restrict__ cat_b,
                                                const float* __restrict__ beta,
                                                const float* __restrict__ gamma,
                                                float* __restrict__ out) {
  const int b  = blockIdx.y;
  const int p0 = blockIdx.x * CHUNK;
  const int o  = threadIdx.x * 4;

  // off(i) = i*(257-i)/2 ; find i for p0
  int i = (int)((257.0 - sqrt(257.0 * 257.0 - 8.0 * (double)p0)) * 0.5);
  if (i < 0) i = 0;
  if (i > S_LEN - 1) i = S_LEN - 1;
  while ((i + 1) * (256 - i) / 2 <= p0) ++i;
  while (i * (257 - i) / 2 > p0) --i;

  float4 cb = *(const float4*)(cat_b + o);
  float4 be = *(const float4*)(beta + o);
  float4 ga = *(const float4*)(gamma + o);

  size_t ri = (size_t)(b * S_LEN + i) * NTOT;
  float4 ax = ld_bf4(P + ri + o);
  float4 bx = ld_bf4(P + ri + 768 + o);
  float4 gx = ld_bf4(P + ri + 1536 + o);

#pragma unroll
  for (int t = 0; t < CHUNK; ++t) {
    const int p = p0 + t;
    bool moved = false;
    while ((i + 1) * (256 - i) / 2 <= p) { ++i; moved = true; }
    if (moved) {
      ri = (size_t)(b * S_LEN + i) * NTOT;
      ax = ld_bf4(P + ri + o);
      bx = ld_bf4(P + ri + 768 + o);
      gx = ld_bf4(P + ri + 1536 + o);
    }
    const int j = i + (p - i * (257 - i) / 2);
    const int rowj = b * S_LEN + j;
    float4 ay = ld_bf4(P + (size_t)rowj * NTOT + 2304 + o);
    float4 yv = *(const float4*)(Yf + (size_t)rowj * H_DIM + o);
    const float m  = mean[rowj];
    const float iv = inv[rowj];
    float4 rr;
    rr.x = 0.5f * (fmaxf(ax.x + ay.x + cb.x, 0.f) + (yv.x - m) * iv * (gx.x + ga.x) + bx.x + be.x);
    rr.y = 0.5f * (fmaxf(ax.y + ay.y + cb.y, 0.f) + (yv.y - m) * iv * (gx.y + ga.y) + bx.y + be.y);
    rr.z = 0.5f * (fmaxf(ax.z + ay.z + cb.z, 0.f) + (yv.z - m) * iv * (gx.z + ga.z) + bx.z + be.z);
    rr.w = 0.5f * (fmaxf(ax.w + ay.w + cb.w, 0.f) + (yv.w - m) * iv * (gx.w + ga.w) + bx.w + be.w);
    *(float4*)(out + ((size_t)b * NPAIR + p) * H_DIM + o) = rr;
  }
}

extern "C" void kernel_launch(void* const* d_in, const int* in_sizes, int n_in,
                              void* d_out, int out_size, void* d_ws, size_t ws_size,
                              hipStream_t stream) {
  const float* x      = (const float*)d_in[0];  // (8,128,768)
  const float* y      = (const float*)d_in[1];  // (8,128,768)
  const float* catW   = (const float*)d_in[2];  // (768,1536)
  const float* catb   = (const float*)d_in[3];  // (768,)
  const float* beta   = (const float*)d_in[4];  // (768,)
  const float* gamma  = (const float*)d_in[5];  // (768,)
  const float* betaW  = (const float*)d_in[6];  // (768,768)
  const float* gammaW = (const float*)d_in[7];  // (768,768)

  // workspace layout (~14.2 MB total)
  char* ws = (char*)d_ws;
  unsigned short* Xb   = (unsigned short*)(ws);              // 1.5 MB
  unsigned short* Yb   = (unsigned short*)(ws + 1572864);    // 1.5 MB
  unsigned short* Wb   = (unsigned short*)(ws + 3145728);    // 4.5 MB
  unsigned short* P    = (unsigned short*)(ws + 7864320);    // 1024*3072*2 = 6.29 MB (bf16)
  float*          mean = (float*)(ws + 14155776);            // 4 KB
  float*          inv  = (float*)(ws + 14159872);            // 4 KB
  float*          out  = (float*)d_out;                      // (8,8256,768) fp32

  prep<<<MROWS + 2304, 256, 0, stream>>>(x, y, catW, betaW, gammaW, Xb, Yb, Wb, mean, inv);
  gemm_bt<<<dim3(16, 48), 256, 0, stream>>>(Xb, Yb, Wb, P);
  epilogue<<<dim3(NPAIR / CHUNK, B_DIM), 192, 0, stream>>>(P, y, mean, inv, catb, beta, gamma, out);
}